// Round 4
// baseline (223.858 us; speedup 1.0000x reference)
//
#include <hip/hip_runtime.h>
#include <stdint.h>

#define NN 4096
#define NC 7
#define SIG1 0.7310585786300049f
#define PER_C 0.001f

// ---------------- ws layout ----------------
#define BITS_OFF   0                          // u64 bits[4096][64] = 2MB
#define CBITS_OFF  (2*1024*1024)              // u64 cbits[4096][64] = 2MB (corr bits, compact idx)
#define DEG_OFF    (4*1024*1024)              // int deg[4096]
#define DIAGP_OFF  (DEG_OFF   + NN*4)         // float diagP[4096]
#define SELF_OFF   (DIAGP_OFF + NN*4)         // int selfq[4096]
#define MIDX_OFF   (SELF_OFF  + NN*4)         // int midx[4096]
#define MLAB_OFF   (MIDX_OFF  + NN*4)         // int mlab[4096]
#define ACC_OFF    (MLAB_OFF  + NN*4)
// acc float-word indices: 0..48 T, 49..55 Ncnt(int), 56..59 masks(2x u64),
//                         60 M(int), 61..76 ce_part[16]

// Build bitset rows + deg + selfq. One wave per row.
__global__ void k_build(const int* __restrict__ adj, unsigned long long* __restrict__ bits,
                        int* __restrict__ deg, int* __restrict__ selfq) {
    int row = blockIdx.x * 4 + (threadIdx.x >> 6);
    int lane = threadIdx.x & 63;
    const int* arow = adj + (size_t)row * NN;
    unsigned long long myw = 0ull;
    #pragma unroll 8
    for (int w = 0; w < 64; w++) {
        unsigned long long m = __ballot(arow[w * 64 + lane] != 0);
        if (lane == w) myw = m;
    }
    bits[(size_t)row * 64 + lane] = myw;
    int d = __popcll(myw);
    #pragma unroll
    for (int o = 32; o > 0; o >>= 1) d += __shfl_down(d, o);
    if (lane == 0) deg[row] = d;
    if (lane == (row >> 6)) selfq[row] = (int)((myw >> (row & 63)) & 1ull);
}

// Blocks 0..15: CE partials + diagP.  Block 16: zero acc, compact scan, Ncnt, M.
__global__ void k_prep2(const float* __restrict__ preds, const int* __restrict__ labels,
                        const int* __restrict__ mask, float* __restrict__ diagP,
                        int* __restrict__ midx, int* __restrict__ mlab,
                        float* __restrict__ acc) {
    int t = threadIdx.x;
    if (blockIdx.x == 16) {
        __shared__ int cnts[256];
        __shared__ int sN[NC];
        if (t < 49) acc[t] = 0.f;                 // T
        if (t >= 56 && t < 60) acc[t] = 0.f;      // masks (2 x u64)
        if (t < NC) sN[t] = 0;
        for (int i = t; i < NN; i += 256) { midx[i] = 0; mlab[i] = 0; }

        int base_n = t * 16;
        int my[16];
        int c = 0;
        #pragma unroll
        for (int k = 0; k < 16; k++) { my[k] = mask[base_n + k]; c += (my[k] != 0); }
        cnts[t] = c;
        __syncthreads();
        for (int s = 1; s < 256; s <<= 1) {
            int v = (t >= s) ? cnts[t - s] : 0;
            __syncthreads();
            cnts[t] += v;
            __syncthreads();
        }
        int pos = cnts[t] - c;  // exclusive prefix
        #pragma unroll
        for (int k = 0; k < 16; k++) {
            if (my[k]) {
                int node = base_n + k;
                int l = labels[node];
                midx[pos] = node;
                mlab[pos] = l;
                atomicAdd(&sN[l], 1);
                pos++;
            }
        }
        __syncthreads();
        if (t < NC) ((int*)acc)[49 + t] = sN[t];
        if (t == 255) ((int*)acc)[60] = cnts[255];   // M
    } else {
        int p = blockIdx.x * 256 + t;
        int l = labels[p];
        const float* pr = preds + p * NC;
        float x[NC];
        #pragma unroll
        for (int c = 0; c < NC; c++) x[c] = pr[c];
        float mx = x[0];
        #pragma unroll
        for (int c = 1; c < NC; c++) mx = fmaxf(mx, x[c]);
        float s = 0.f;
        #pragma unroll
        for (int c = 0; c < NC; c++) s += __expf(x[c] - mx);
        float lse = mx + logf(s);
        float dp = x[l];
        diagP[p] = dp;

        __shared__ float red[256];
        red[t] = lse - dp;
        __syncthreads();
        for (int st = 128; st > 0; st >>= 1) {
            if (t < st) red[t] += red[t + st];
            __syncthreads();
        }
        if (t == 0) acc[61 + blockIdx.x] = red[0];
    }
}

// Correction-bit matrix over compacted nodes:
// cbits[i][w] bit k = adj[midx_i, midx_{64w+k}] & ~adj[midx_{64w+k}, midx_{64w+k}]
// One wave per output u64 word (ballot), persistent over M*nW words.
__global__ void k_pq(const unsigned long long* __restrict__ bits,
                     const int* __restrict__ midx, const int* __restrict__ selfq,
                     const int* __restrict__ Mptr, unsigned long long* __restrict__ cbits) {
    int M = Mptr[0];
    int nW = (M + 63) >> 6;
    int lane = threadIdx.x & 63;
    int wave = (blockIdx.x * blockDim.x + threadIdx.x) >> 6;
    int nwaves = (gridDim.x * blockDim.x) >> 6;
    int total = M * nW;
    for (int wid = wave; wid < total; wid += nwaves) {
        int i = wid / nW, w = wid - i * nW;
        int q = w * 64 + lane;
        int bit = 0;
        if (q < M) {
            int col = midx[q];
            const unsigned long long* row = bits + (size_t)midx[i] * 64;
            bit = (int)((row[col >> 6] >> (col & 63)) & 1ull) & (selfq[col] ^ 1);
        }
        unsigned long long word = __ballot(bit != 0);
        if (lane == 0) cbits[(size_t)i * 64 + w] = word;
    }
}

// Pair kernel: 64 threads (ONE wave) per block, 64x64 tile, 8x8 register tile.
// K staged in 2 halves of 16 x 16B chunks; swizzle sc = lc ^ ((row>>3)&7):
// a-reads (8 ty rows) and b-reads (8 tx rows) each hit 8 distinct bank-groups.
// Persistent loop over ceil(M/64)^2 tiles; T/mask flushed once per block.
__launch_bounds__(64, 1)
__global__ void k_pairs(const unsigned long long* __restrict__ bits,
                        const float* __restrict__ preds,
                        const int* __restrict__ deg,
                        const float* __restrict__ diagP,
                        const unsigned long long* __restrict__ cbits,
                        const int* __restrict__ midx,
                        const int* __restrict__ mlab,
                        const int* __restrict__ Mptr,
                        float* __restrict__ T,
                        unsigned long long* __restrict__ g_masks) {
    __shared__ ulonglong2 lp[64 * 16];
    __shared__ ulonglong2 lq[64 * 16];
    __shared__ float predsQ[NC * 65];   // stride 65: decorrelate banks across label rows
    __shared__ float diagPp[64];
    __shared__ int labP[64], labQ[64], degP[64], sMp[64], sMq[64];
    __shared__ unsigned long long PQw[64];
    __shared__ float T_lds[49];

    int M = Mptr[0];
    int tpq = (M + 63) >> 6;
    int nT = tpq * tpq;
    int t = threadIdx.x;
    int tx = t & 7, ty = t >> 3;

    if (t < 49) T_lds[t] = 0.f;
    unsigned long long lsub = 0ull, linter = 0ull;

    for (int tile = blockIdx.x; tile < nT; tile += gridDim.x) {
        int trow = tile / tpq;
        int p0 = trow << 6, q0 = (tile - trow * tpq) << 6;
        __syncthreads();   // prev tile fully consumed (trivial: 1 wave)
        {
            int pi = midx[p0 + t], qi = midx[q0 + t];
            sMp[t] = pi; sMq[t] = qi;
            diagPp[t] = diagP[pi];
            degP[t]   = deg[pi];
            labP[t]   = mlab[p0 + t];
            labQ[t]   = mlab[q0 + t];
            PQw[t]    = cbits[(size_t)(p0 + t) * 64 + (q0 >> 6)];
            #pragma unroll
            for (int c = 0; c < NC; c++) predsQ[c * 65 + t] = preds[qi * NC + c];
        }

        int cnt[8][8];
        #pragma unroll
        for (int i = 0; i < 8; i++)
            #pragma unroll
            for (int j = 0; j < 8; j++) cnt[i][j] = 0;

        for (int h = 0; h < 2; h++) {
            __syncthreads();
            #pragma unroll
            for (int it = 0; it < 16; it++) {
                int idx = t + 64 * it;          // 0..1023: 64 rows x 16 chunks
                int row = idx >> 4, lc = idx & 15;
                int sc = lc ^ ((row >> 3) & 7);
                lp[row * 16 + sc] = *(const ulonglong2*)&bits[(size_t)sMp[row] * 64 + 32 * h + 2 * lc];
                lq[row * 16 + sc] = *(const ulonglong2*)&bits[(size_t)sMq[row] * 64 + 32 * h + 2 * lc];
            }
            __syncthreads();

            const ulonglong2* Ap = lp + ty * 128;   // row 8ty+i at chunk base ty*128 + i*16
            const ulonglong2* Bp = lq + tx * 128;
            #pragma unroll 2
            for (int c = 0; c < 16; c++) {
                ulonglong2 a[8], b[8];
                int sa = c ^ ty, sb = c ^ tx;
                #pragma unroll
                for (int i = 0; i < 8; i++) a[i] = Ap[i * 16 + sa];
                #pragma unroll
                for (int j = 0; j < 8; j++) b[j] = Bp[j * 16 + sb];
                #pragma unroll
                for (int i = 0; i < 8; i++)
                    #pragma unroll
                    for (int j = 0; j < 8; j++)
                        cnt[i][j] += __popcll(a[i].x & b[j].x) + __popcll(a[i].y & b[j].y);
            }
        }

        // epilogue: register-only correction bits + per-pair E*v into LDS bins
        unsigned int pqb[8];
        int lqr[8];
        #pragma unroll
        for (int i = 0; i < 8; i++) pqb[i] = (unsigned int)((PQw[8 * ty + i] >> (8 * tx)) & 0xffull);
        #pragma unroll
        for (int j = 0; j < 8; j++) lqr[j] = labQ[8 * tx + j];

        #pragma unroll
        for (int i = 0; i < 8; i++) {
            int pl = 8 * ty + i;
            if (p0 + pl >= M) continue;
            int lp_ = labP[pl], dgp = degP[pl];
            float dPp = diagPp[pl];
            #pragma unroll
            for (int j = 0; j < 8; j++) {
                int ql = 8 * tx + j;
                if (q0 + ql >= M) continue;
                int inter = cnt[i][j];
                int sub = dgp - inter - (int)((pqb[i] >> j) & 1u);
                int lq_ = lqr[j];
                int bidx = lp_ * 7 + lq_;
                if (sub > 0)   lsub   |= 1ull << bidx;
                if (inter > 0) linter |= 1ull << bidx;
                if (lp_ != lq_) {
                    float arg = (1.f + SIG1 * (float)sub) / (1.f + SIG1 * (float)inter);
                    float v = 1.f / (1.f + __expf(arg));            // 1 - sigmoid(arg)
                    float E = __expf(predsQ[lp_ * 65 + ql] - dPp);  // exp(G - diagP)
                    atomicAdd(&T_lds[bidx], E * v);
                }
            }
        }
    }

    __syncthreads();
    #pragma unroll
    for (int o = 32; o > 0; o >>= 1) {
        lsub   |= __shfl_down(lsub, o);
        linter |= __shfl_down(linter, o);
    }
    if (t == 0) {
        if (lsub)   atomicOr(&g_masks[0], lsub);
        if (linter) atomicOr(&g_masks[1], linter);
    }
    if (t < 49) { float v = T_lds[t]; if (v != 0.f) atomicAdd(&T[t], v); }
}

__global__ void k_final(const float* __restrict__ acc, float* __restrict__ out) {
    if (threadIdx.x == 0 && blockIdx.x == 0) {
        const float* T = acc;
        const int* Ncnt = (const int*)(acc + 49);
        const unsigned long long* m = (const unsigned long long*)(acc + 56);
        float ce = 0.f;
        for (int b = 0; b < 16; b++) ce += acc[61 + b];
        ce /= (float)NN;
        unsigned long long hb = m[0] & m[1];
        float invN[NC];
        #pragma unroll
        for (int c = 0; c < NC; c++) { int n = Ncnt[c]; invN[c] = (n > 0) ? 1.f / (float)n : 0.f; }
        float lp = 0.f;
        for (int c1 = 0; c1 < NC; c1++)
            for (int c2 = 0; c2 < NC; c2++) {
                int b = c1 * 7 + c2;
                if ((hb >> b) & 1ull) lp += invN[c1] * invN[c2] * T[b];
            }
        out[0] = ce + PER_C * lp;
    }
}

extern "C" void kernel_launch(void* const* d_in, const int* in_sizes, int n_in,
                              void* d_out, int out_size, void* d_ws, size_t ws_size,
                              hipStream_t stream) {
    const float* preds  = (const float*)d_in[0];
    const int*   labels = (const int*)d_in[1];
    const int*   mask   = (const int*)d_in[2];
    const int*   adj    = (const int*)d_in[3];
    float* out = (float*)d_out;

    char* ws = (char*)d_ws;
    unsigned long long* bits  = (unsigned long long*)(ws + BITS_OFF);
    unsigned long long* cbits = (unsigned long long*)(ws + CBITS_OFF);
    int*   deg   = (int*)(ws + DEG_OFF);
    float* diagP = (float*)(ws + DIAGP_OFF);
    int*   selfq = (int*)(ws + SELF_OFF);
    int*   midx  = (int*)(ws + MIDX_OFF);
    int*   mlab  = (int*)(ws + MLAB_OFF);
    float* acc   = (float*)(ws + ACC_OFF);
    float* T       = acc;
    const int* Mptr = (const int*)(acc + 60);
    unsigned long long* g_masks = (unsigned long long*)(acc + 56);

    k_build<<<1024, 256, 0, stream>>>(adj, bits, deg, selfq);
    k_prep2<<<17, 256, 0, stream>>>(preds, labels, mask, diagP, midx, mlab, acc);
    k_pq<<<1024, 256, 0, stream>>>(bits, midx, selfq, Mptr, cbits);
    k_pairs<<<1024, 64, 0, stream>>>(bits, preds, deg, diagP, cbits, midx, mlab, Mptr, T, g_masks);
    k_final<<<1, 64, 0, stream>>>(acc, out);
}